// Round 13
// baseline (112.208 us; speedup 1.0000x reference)
//
#include <hip/hip_runtime.h>
#include <math.h>

#define BB 4
#define SS 4096
#define HH 1024
#define NH 16
#define DK 64
#define NMODES 4
#define NSB 128             // s-chunks for DFT kernel
#define SCHUNK (SS/NSB)     // 32
#define PPLANE ((size_t)BB * NSB * HH)   // one q-plane of P: 512K floats
#define TWO_PI 6.28318530717958647692f
#define DIAG_REP 7

typedef float nfloat4 __attribute__((ext_vector_type(4)));  // native vec for nontemporal

// ---------------- Kernel A: partial 4-mode DFT of x over s ----------------
// 512 blocks x 256 thr, each block reads 32 FULL 4 KB rows (contiguous
// float4 per wave). P stored as 8 planes: P[q*PPLANE + (b*NSB+sb)*HH + c].
__global__ __launch_bounds__(256) void kA_dft(const float* __restrict__ x,
                                              const int* __restrict__ index,
                                              float* __restrict__ P) {
    __shared__ float tab[SCHUNK * 8];
    int t  = threadIdx.x;
    int sb = blockIdx.x & (NSB - 1);
    int b  = blockIdx.x >> 7;

    // fill trig table: 32 rows x 4 modes = 128 entries
    if (t < SCHUNK * NMODES) {
        int sl = t >> 2, m = t & 3;
        int k  = index[m];
        int sv = sb * SCHUNK + sl;
        int r  = (k * sv) & (SS - 1);          // exact phase mod S
        float ang = (float)r * (TWO_PI / (float)SS);
        float sn, cs;
        sincosf(ang, &sn, &cs);
        tab[sl * 8 + m * 2]     = cs;
        tab[sl * 8 + m * 2 + 1] = sn;
    }
    __syncthreads();

    int c0 = t * 4;
    float acc[4][8];
    #pragma unroll
    for (int e = 0; e < 4; ++e)
        #pragma unroll
        for (int q = 0; q < 8; ++q) acc[e][q] = 0.f;

    const float* xp = x + ((size_t)(b * SS + sb * SCHUNK)) * HH + c0;
    #pragma unroll 8
    for (int r = 0; r < SCHUNK; ++r) {
        float4 xv = *(const float4*)(xp + (size_t)r * HH);
        float4 t0 = *(const float4*)&tab[r * 8];      // broadcast (uniform addr)
        float4 t1 = *(const float4*)&tab[r * 8 + 4];
        float xe;
        #pragma unroll
        for (int e = 0; e < 4; ++e) {
            xe = (e == 0) ? xv.x : (e == 1) ? xv.y : (e == 2) ? xv.z : xv.w;
            acc[e][0] += xe * t0.x;  acc[e][1] -= xe * t0.y;  // G = sum x*(cos - i sin)
            acc[e][2] += xe * t0.z;  acc[e][3] -= xe * t0.w;
            acc[e][4] += xe * t1.x;  acc[e][5] -= xe * t1.y;
            acc[e][6] += xe * t1.z;  acc[e][7] -= xe * t1.w;
        }
    }
    size_t base = (size_t)(b * NSB + sb) * HH + c0;
    #pragma unroll
    for (int q = 0; q < 8; ++q) {
        *(float4*)&P[q * PPLANE + base] =
            make_float4(acc[0][q], acc[1][q], acc[2][q], acc[3][q]);
    }
}

// ---------------- Kernel A2: deterministic reduction of partials ----------
// DIAG: body repeated 7x. 512 blocks x 256 thr; 4 threads per output element.
__global__ __launch_bounds__(256) void kA2_reduce(const float* __restrict__ P,
                                                  float* __restrict__ G) {
    for (int rep = 0; rep < DIAG_REP; ++rep) {
        int i = blockIdx.x * 256 + threadIdx.x;   // 0..131071
        int g = i >> 2;                           // element 0..32767
        int quarter = i & 3;
        int j = g & (HH - 1);
        int q = (g >> 10) & 7;
        int b = g >> 13;
        const float* pp = P + q * PPLANE + (size_t)b * NSB * HH
                        + (size_t)(quarter * (NSB / 4)) * HH + j;
        float s = 0.f;
        #pragma unroll 16
        for (int sb = 0; sb < NSB / 4; ++sb)
            s += pp[(size_t)sb * HH];
        s += __shfl_xor(s, 1);
        s += __shfl_xor(s, 2);
        if (quarter == 0) G[g] = s;
        asm volatile("" ::: "memory");
    }
}

// ---------------- Kernel B: xm[b,c,m] = Wq[c,:] . G[b,:,m] + bias ----------
// DIAG: body repeated 7x. 256 blocks: (b, cb) with 16 channels per block.
__global__ __launch_bounds__(256) void kB_proj(const float* __restrict__ Wq,
                                               const float* __restrict__ bq,
                                               const int* __restrict__ index,
                                               const float* __restrict__ G,
                                               float* __restrict__ XM) {
    __shared__ float Gs[8 * HH];   // 32 KB, plane layout [q][j]
    int t  = threadIdx.x;
    int cb = blockIdx.x & 63;
    int b  = blockIdx.x >> 6;

    for (int rep = 0; rep < DIAG_REP; ++rep) {
        {
            const float4* gsrc = (const float4*)(G + (size_t)b * 8 * HH);
            float4* gdst = (float4*)Gs;
            for (int u = t; u < 2 * HH; u += 256) gdst[u] = gsrc[u];
        }
        __syncthreads();

        int cl = t >> 4, jq = t & 15;
        int c = cb * 16 + cl;
        float acc[8] = {0.f,0.f,0.f,0.f,0.f,0.f,0.f,0.f};
        for (int j0 = jq * 4; j0 < HH; j0 += 64) {
            float4 wv = *(const float4*)&Wq[(size_t)c * HH + j0];
            #pragma unroll
            for (int q = 0; q < 8; ++q) {
                float4 gv = *(const float4*)&Gs[q * HH + j0];
                acc[q] += wv.x * gv.x + wv.y * gv.y + wv.z * gv.z + wv.w * gv.w;
            }
        }
        #pragma unroll
        for (int q = 0; q < 8; ++q) {
            acc[q] += __shfl_xor(acc[q], 1);
            acc[q] += __shfl_xor(acc[q], 2);
            acc[q] += __shfl_xor(acc[q], 4);
            acc[q] += __shfl_xor(acc[q], 8);
        }
        if (jq == 0) {
            float bias = bq[c];
            #pragma unroll
            for (int m = 0; m < NMODES; ++m)
                if (index[m] == 0) acc[2 * m] += bias * (float)SS;  // sum_s e^0 = S
            float* o = XM + ((size_t)(b * HH + c)) * 8;
            *(float4*)o       = make_float4(acc[0], acc[1], acc[2], acc[3]);
            *(float4*)(o + 4) = make_float4(acc[4], acc[5], acc[6], acc[7]);
        }
        __syncthreads();
        asm volatile("" ::: "memory");
    }
}

// ---------------- Kernel C: per-head complex mode-mix + irfft coefficients -
// DIAG: body repeated 7x.
#define KC_IQ 8
#define KC_II (DK / KC_IQ)   // 8
__global__ __launch_bounds__(512) void kC_modes(const float* __restrict__ wr,
                                                const float* __restrict__ wi,
                                                const float* __restrict__ XM,
                                                float* __restrict__ CF) {
    __shared__ float xs[DK * 8];             // 2 KB: xm slice for (b,h)
    __shared__ float red[KC_IQ][DK][9];      // padded to 9: conflict-free
    int t = threadIdx.x;
    int o = t & 63, iq = t >> 6;
    int h = blockIdx.x & 15;
    int b = blockIdx.x >> 4;

    for (int rep = 0; rep < DIAG_REP; ++rep) {
        for (int u = t; u < DK * 8; u += 512)
            xs[u] = XM[((size_t)(b * HH + h * DK)) * 8 + u];
        __syncthreads();

        float re[4] = {0.f,0.f,0.f,0.f}, im[4] = {0.f,0.f,0.f,0.f};
        #pragma unroll
        for (int ii = 0; ii < KC_II; ++ii) {
            int i = iq * KC_II + ii;
            float4 wrv = *(const float4*)&wr[(((size_t)(h * DK + i)) * DK + o) * 4];
            float4 wiv = *(const float4*)&wi[(((size_t)(h * DK + i)) * DK + o) * 4];
            float xr, xi;
            xr = xs[i * 8 + 0]; xi = xs[i * 8 + 1];
            re[0] += xr * wrv.x - xi * wiv.x;  im[0] += xr * wiv.x + xi * wrv.x;
            xr = xs[i * 8 + 2]; xi = xs[i * 8 + 3];
            re[1] += xr * wrv.y - xi * wiv.y;  im[1] += xr * wiv.y + xi * wrv.y;
            xr = xs[i * 8 + 4]; xi = xs[i * 8 + 5];
            re[2] += xr * wrv.z - xi * wiv.z;  im[2] += xr * wiv.z + xi * wrv.z;
            xr = xs[i * 8 + 6]; xi = xs[i * 8 + 7];
            re[3] += xr * wrv.w - xi * wiv.w;  im[3] += xr * wiv.w + xi * wrv.w;
        }
        #pragma unroll
        for (int m = 0; m < 4; ++m) {
            red[iq][o][2 * m]     = re[m];
            red[iq][o][2 * m + 1] = im[m];
        }
        __syncthreads();
        if (iq == 0) {
            float rr[8];
            #pragma unroll
            for (int q = 0; q < 8; ++q) {
                float s = 0.f;
                #pragma unroll
                for (int g = 0; g < KC_IQ; ++g) s += red[g][o][q];
                rr[q] = s;
            }
            int co = o * NH + h;               // faithful permute(0,3,2,1) flatten
            const float inv = 1.0f / (float)SS;
            float* cp = CF + ((size_t)(b * HH + co)) * 8;
            cp[0] =  rr[0] * inv;              // irfft ignores Im(c0) (pocketfft c2r)
            cp[1] =  2.0f * rr[2] * inv;
            cp[2] = -2.0f * rr[3] * inv;
            cp[3] =  2.0f * rr[4] * inv;
            cp[4] = -2.0f * rr[5] * inv;
            cp[5] =  2.0f * rr[6] * inv;
            cp[6] = -2.0f * rr[7] * inv;
            cp[7] =  0.0f;
        }
        __syncthreads();
        asm volatile("" ::: "memory");
    }
}

// ---------------- Kernel D: low-rank irfft + residual + LayerNorm ---------
// 8 rows/block; x loads issued first; nontemporal out stores.
#define KD_ROWS 8
__global__ __launch_bounds__(256) void kD_out(const float* __restrict__ x,
                                              const float* __restrict__ CF,
                                              const float* __restrict__ gamma,
                                              const float* __restrict__ beta,
                                              float* __restrict__ out) {
    __shared__ float red[4][KD_ROWS][2];
    int t  = threadIdx.x;
    int b  = blockIdx.x >> 9;
    int s0 = (blockIdx.x & 511) * KD_ROWS;
    int c0 = t * 4;
    int w = t >> 6, lane = t & 63;

    // issue the long-latency x loads first
    float4 yv[KD_ROWS];
    #pragma unroll
    for (int r = 0; r < KD_ROWS; ++r) {
        int s = s0 + r;
        yv[r] = *(const float4*)&x[((size_t)(b * SS + s)) * HH + c0];
    }

    float myc, mys;
    {
        float ang = (float)(s0 + (t & 7)) * (TWO_PI / (float)SS);
        sincosf(ang, &mys, &myc);
    }

    const float* cp = CF + (size_t)b * HH * 8 + (size_t)c0 * 8;
    float4 cfa[8];
    #pragma unroll
    for (int e = 0; e < 4; ++e) {
        cfa[2 * e]     = *(const float4*)(cp + e * 8);
        cfa[2 * e + 1] = *(const float4*)(cp + e * 8 + 4);
    }
    float4 g4 = *(const float4*)&gamma[c0];
    float4 b4 = *(const float4*)&beta[c0];

    float sm[KD_ROWS], sq[KD_ROWS];
    #pragma unroll
    for (int r = 0; r < KD_ROWS; ++r) {
        float c1 = __shfl(myc, r), s1 = __shfl(mys, r);
        float c2 = c1 * c1 - s1 * s1, s2 = 2.f * s1 * c1;
        float c3 = c2 * c1 - s2 * s1, s3 = s2 * c1 + c2 * s1;
        float ye[4];
        #pragma unroll
        for (int e = 0; e < 4; ++e) {
            float xe = (e == 0) ? yv[r].x : (e == 1) ? yv[r].y
                     : (e == 2) ? yv[r].z : yv[r].w;
            float4 A = cfa[2 * e], Bv = cfa[2 * e + 1];
            ye[e] = xe + A.x + A.y * c1 + A.z * s1 + A.w * c2
                       + Bv.x * s2 + Bv.y * c3 + Bv.z * s3;
        }
        yv[r] = make_float4(ye[0], ye[1], ye[2], ye[3]);
        sm[r] = ye[0] + ye[1] + ye[2] + ye[3];
        sq[r] = ye[0]*ye[0] + ye[1]*ye[1] + ye[2]*ye[2] + ye[3]*ye[3];
    }
    #pragma unroll
    for (int off = 1; off < 64; off <<= 1) {
        #pragma unroll
        for (int r = 0; r < KD_ROWS; ++r) {
            sm[r] += __shfl_xor(sm[r], off);
            sq[r] += __shfl_xor(sq[r], off);
        }
    }
    if (lane == 0) {
        #pragma unroll
        for (int r = 0; r < KD_ROWS; ++r) {
            red[w][r][0] = sm[r];
            red[w][r][1] = sq[r];
        }
    }
    __syncthreads();
    #pragma unroll
    for (int r = 0; r < KD_ROWS; ++r) {
        int s = s0 + r;
        float tot  = red[0][r][0] + red[1][r][0] + red[2][r][0] + red[3][r][0];
        float totq = red[0][r][1] + red[1][r][1] + red[2][r][1] + red[3][r][1];
        float mean = tot * (1.0f / (float)HH);
        float var  = totq * (1.0f / (float)HH) - mean * mean;
        float rs = rsqrtf(var + 1e-5f);
        nfloat4 o4;
        o4.x = (yv[r].x - mean) * rs * g4.x + b4.x;
        o4.y = (yv[r].y - mean) * rs * g4.y + b4.y;
        o4.z = (yv[r].z - mean) * rs * g4.z + b4.z;
        o4.w = (yv[r].w - mean) * rs * g4.w + b4.w;
        __builtin_nontemporal_store(o4,
            (nfloat4*)&out[((size_t)(b * SS + s)) * HH + c0]);
    }
}

extern "C" void kernel_launch(void* const* d_in, const int* in_sizes, int n_in,
                              void* d_out, int out_size, void* d_ws, size_t ws_size,
                              hipStream_t stream) {
    const float* x     = (const float*)d_in[0];
    const float* Wq    = (const float*)d_in[1];
    const float* bq    = (const float*)d_in[2];
    const float* wr    = (const float*)d_in[3];
    const float* wi    = (const float*)d_in[4];
    const float* gamma = (const float*)d_in[5];
    const float* beta  = (const float*)d_in[6];
    const int*   index = (const int*)d_in[7];
    float* out = (float*)d_out;
    float* ws  = (float*)d_ws;

    const size_t nP     = PPLANE * 8;          // 4M floats (16 MB)
    const size_t nSmall = (size_t)BB * HH * 8; // 32,768 floats (128 KB)

    float *P, *G, *XM, *CF;
    if (ws_size >= (nP + 3 * nSmall) * sizeof(float)) {
        P  = ws;
        G  = P + nP;
        XM = G + nSmall;
        CF = XM + nSmall;
    } else {
        // fallback: P lives in d_out (consumed by kA2 before kD writes out)
        P  = out;
        G  = ws;
        XM = G + nSmall;
        CF = XM + nSmall;
    }

    hipLaunchKernelGGL(kA_dft,     dim3(BB * NSB), dim3(256), 0, stream, x, index, P);
    hipLaunchKernelGGL(kA2_reduce, dim3(BB * HH * 8 * 4 / 256), dim3(256), 0, stream, P, G);
    hipLaunchKernelGGL(kB_proj,    dim3(BB * 64), dim3(256), 0, stream, Wq, bq, index, G, XM);
    hipLaunchKernelGGL(kC_modes,   dim3(BB * NH), dim3(512), 0, stream, wr, wi, XM, CF);
    hipLaunchKernelGGL(kD_out,     dim3(BB * (SS / KD_ROWS)), dim3(256), 0, stream, x, CF, gamma, beta, out);
}

// Round 14
// 58.077 us; speedup vs baseline: 1.9321x; 1.9321x over previous
//
#include <hip/hip_runtime.h>
#include <math.h>

#define BB 4
#define SS 4096
#define HH 1024
#define NH 16
#define DK 64
#define NMODES 4
#define NSB 128             // s-chunks for DFT kernel
#define SCHUNK (SS/NSB)     // 32
#define PPLANE ((size_t)BB * NSB * HH)   // one q-plane of P: 512K floats
#define TWO_PI 6.28318530717958647692f

// ---------------- Kernel A: partial 4-mode DFT of x over s ----------------
// 512 blocks x 256 thr, each block reads 32 FULL 4 KB rows (contiguous
// float4 per wave). P stored as 8 planes: P[q*PPLANE + (b*NSB+sb)*HH + c].
__global__ __launch_bounds__(256) void kA_dft(const float* __restrict__ x,
                                              const int* __restrict__ index,
                                              float* __restrict__ P) {
    __shared__ float tab[SCHUNK * 8];
    int t  = threadIdx.x;
    int sb = blockIdx.x & (NSB - 1);
    int b  = blockIdx.x >> 7;

    // fill trig table: 32 rows x 4 modes = 128 entries
    if (t < SCHUNK * NMODES) {
        int sl = t >> 2, m = t & 3;
        int k  = index[m];
        int sv = sb * SCHUNK + sl;
        int r  = (k * sv) & (SS - 1);          // exact phase mod S
        float ang = (float)r * (TWO_PI / (float)SS);
        float sn, cs;
        sincosf(ang, &sn, &cs);
        tab[sl * 8 + m * 2]     = cs;
        tab[sl * 8 + m * 2 + 1] = sn;
    }
    __syncthreads();

    int c0 = t * 4;
    float acc[4][8];
    #pragma unroll
    for (int e = 0; e < 4; ++e)
        #pragma unroll
        for (int q = 0; q < 8; ++q) acc[e][q] = 0.f;

    const float* xp = x + ((size_t)(b * SS + sb * SCHUNK)) * HH + c0;
    #pragma unroll 8
    for (int r = 0; r < SCHUNK; ++r) {
        float4 xv = *(const float4*)(xp + (size_t)r * HH);
        float4 t0 = *(const float4*)&tab[r * 8];      // broadcast (uniform addr)
        float4 t1 = *(const float4*)&tab[r * 8 + 4];
        float xe;
        #pragma unroll
        for (int e = 0; e < 4; ++e) {
            xe = (e == 0) ? xv.x : (e == 1) ? xv.y : (e == 2) ? xv.z : xv.w;
            acc[e][0] += xe * t0.x;  acc[e][1] -= xe * t0.y;  // G = sum x*(cos - i sin)
            acc[e][2] += xe * t0.z;  acc[e][3] -= xe * t0.w;
            acc[e][4] += xe * t1.x;  acc[e][5] -= xe * t1.y;
            acc[e][6] += xe * t1.z;  acc[e][7] -= xe * t1.w;
        }
    }
    size_t base = (size_t)(b * NSB + sb) * HH + c0;
    #pragma unroll
    for (int q = 0; q < 8; ++q) {
        *(float4*)&P[q * PPLANE + base] =
            make_float4(acc[0][q], acc[1][q], acc[2][q], acc[3][q]);
    }
}

// ---------------- Kernel A2: deterministic reduction of partials ----------
// 512 blocks x 256 thr; 4 threads per output element (s-split), shfl combine.
// output G in 8 planes per batch: G[(b*8+q)*HH + j]
__global__ __launch_bounds__(256) void kA2_reduce(const float* __restrict__ P,
                                                  float* __restrict__ G) {
    int i = blockIdx.x * 256 + threadIdx.x;   // 0..131071
    int g = i >> 2;                           // element 0..32767
    int quarter = i & 3;
    int j = g & (HH - 1);
    int q = (g >> 10) & 7;
    int b = g >> 13;
    const float* pp = P + q * PPLANE + (size_t)b * NSB * HH
                    + (size_t)(quarter * (NSB / 4)) * HH + j;
    float s = 0.f;
    #pragma unroll 16
    for (int sb = 0; sb < NSB / 4; ++sb)
        s += pp[(size_t)sb * HH];
    s += __shfl_xor(s, 1);
    s += __shfl_xor(s, 2);
    if (quarter == 0) G[g] = s;
}

// ---------------- Kernel B: xm[b,c,m] = Wq[c,:] . G[b,:,m] + bias ----------
// 1024 blocks x 256 thr: (b, cb), 4 channels/block (one WAVE per channel),
// 64-way j-split; G read directly from L2/L3 (1 KB/wave coalesced), no LDS.
// 4096 waves -> 16 waves/CU: latency fully hidden.
__global__ __launch_bounds__(256) void kB_proj(const float* __restrict__ Wq,
                                               const float* __restrict__ bq,
                                               const int* __restrict__ index,
                                               const float* __restrict__ G,
                                               float* __restrict__ XM) {
    int t  = threadIdx.x;
    int cb = blockIdx.x & 255;
    int b  = blockIdx.x >> 8;
    int cl = t >> 6;          // 0..3: wave index == channel
    int jq = t & 63;
    int c  = cb * 4 + cl;

    const float* wrow = Wq + (size_t)c * HH;
    const float* gb   = G + (size_t)b * 8 * HH;

    float acc[8] = {0.f,0.f,0.f,0.f,0.f,0.f,0.f,0.f};
    #pragma unroll
    for (int it = 0; it < 4; ++it) {
        int j0 = jq * 4 + it * 256;
        float4 wv = *(const float4*)&wrow[j0];
        #pragma unroll
        for (int q = 0; q < 8; ++q) {
            float4 gv = *(const float4*)&gb[q * HH + j0];
            acc[q] += wv.x * gv.x + wv.y * gv.y + wv.z * gv.z + wv.w * gv.w;
        }
    }
    #pragma unroll
    for (int q = 0; q < 8; ++q) {
        acc[q] += __shfl_xor(acc[q], 1);
        acc[q] += __shfl_xor(acc[q], 2);
        acc[q] += __shfl_xor(acc[q], 4);
        acc[q] += __shfl_xor(acc[q], 8);
        acc[q] += __shfl_xor(acc[q], 16);
        acc[q] += __shfl_xor(acc[q], 32);
    }
    if (jq == 0) {
        float bias = bq[c];
        #pragma unroll
        for (int m = 0; m < NMODES; ++m)
            if (index[m] == 0) acc[2 * m] += bias * (float)SS;  // sum_s e^0 = S
        float* o = XM + ((size_t)(b * HH + c)) * 8;
        *(float4*)o       = make_float4(acc[0], acc[1], acc[2], acc[3]);
        *(float4*)(o + 4) = make_float4(acc[4], acc[5], acc[6], acc[7]);
    }
}

// ---------------- Kernel C: per-head complex mode-mix + irfft coefficients -
#define KC_IQ 8
#define KC_II (DK / KC_IQ)   // 8
__global__ __launch_bounds__(512) void kC_modes(const float* __restrict__ wr,
                                                const float* __restrict__ wi,
                                                const float* __restrict__ XM,
                                                float* __restrict__ CF) {
    __shared__ float xs[DK * 8];             // 2 KB: xm slice for (b,h)
    __shared__ float red[KC_IQ][DK][9];      // padded to 9: conflict-free
    int t = threadIdx.x;
    int o = t & 63, iq = t >> 6;
    int h = blockIdx.x & 15;
    int b = blockIdx.x >> 4;
    for (int u = t; u < DK * 8; u += 512)
        xs[u] = XM[((size_t)(b * HH + h * DK)) * 8 + u];
    __syncthreads();

    float re[4] = {0.f,0.f,0.f,0.f}, im[4] = {0.f,0.f,0.f,0.f};
    #pragma unroll
    for (int ii = 0; ii < KC_II; ++ii) {
        int i = iq * KC_II + ii;
        float4 wrv = *(const float4*)&wr[(((size_t)(h * DK + i)) * DK + o) * 4];
        float4 wiv = *(const float4*)&wi[(((size_t)(h * DK + i)) * DK + o) * 4];
        float xr, xi;
        xr = xs[i * 8 + 0]; xi = xs[i * 8 + 1];
        re[0] += xr * wrv.x - xi * wiv.x;  im[0] += xr * wiv.x + xi * wrv.x;
        xr = xs[i * 8 + 2]; xi = xs[i * 8 + 3];
        re[1] += xr * wrv.y - xi * wiv.y;  im[1] += xr * wiv.y + xi * wrv.y;
        xr = xs[i * 8 + 4]; xi = xs[i * 8 + 5];
        re[2] += xr * wrv.z - xi * wiv.z;  im[2] += xr * wiv.z + xi * wrv.z;
        xr = xs[i * 8 + 6]; xi = xs[i * 8 + 7];
        re[3] += xr * wrv.w - xi * wiv.w;  im[3] += xr * wiv.w + xi * wrv.w;
    }
    #pragma unroll
    for (int m = 0; m < 4; ++m) {
        red[iq][o][2 * m]     = re[m];
        red[iq][o][2 * m + 1] = im[m];
    }
    __syncthreads();
    if (iq == 0) {
        float rr[8];
        #pragma unroll
        for (int q = 0; q < 8; ++q) {
            float s = 0.f;
            #pragma unroll
            for (int g = 0; g < KC_IQ; ++g) s += red[g][o][q];
            rr[q] = s;
        }
        int co = o * NH + h;               // faithful permute(0,3,2,1) flatten
        const float inv = 1.0f / (float)SS;
        float* cp = CF + ((size_t)(b * HH + co)) * 8;
        cp[0] =  rr[0] * inv;              // irfft ignores Im(c0) (pocketfft c2r)
        cp[1] =  2.0f * rr[2] * inv;
        cp[2] = -2.0f * rr[3] * inv;
        cp[3] =  2.0f * rr[4] * inv;
        cp[4] = -2.0f * rr[5] * inv;
        cp[5] =  2.0f * rr[6] * inv;
        cp[6] = -2.0f * rr[7] * inv;
        cp[7] =  0.0f;
    }
}

// ---------------- Kernel D: low-rank irfft + residual + LayerNorm ---------
// 8 rows/block; x loads issued first; PLAIN stores (NT reverted — A/B test:
// normal stores retire into L2/L3 and drain after kernel end).
#define KD_ROWS 8
__global__ __launch_bounds__(256) void kD_out(const float* __restrict__ x,
                                              const float* __restrict__ CF,
                                              const float* __restrict__ gamma,
                                              const float* __restrict__ beta,
                                              float* __restrict__ out) {
    __shared__ float red[4][KD_ROWS][2];
    int t  = threadIdx.x;
    int b  = blockIdx.x >> 9;
    int s0 = (blockIdx.x & 511) * KD_ROWS;
    int c0 = t * 4;
    int w = t >> 6, lane = t & 63;

    // issue the long-latency x loads first
    float4 yv[KD_ROWS];
    #pragma unroll
    for (int r = 0; r < KD_ROWS; ++r) {
        int s = s0 + r;
        yv[r] = *(const float4*)&x[((size_t)(b * SS + s)) * HH + c0];
    }

    float myc, mys;
    {
        float ang = (float)(s0 + (t & 7)) * (TWO_PI / (float)SS);
        sincosf(ang, &mys, &myc);
    }

    const float* cp = CF + (size_t)b * HH * 8 + (size_t)c0 * 8;
    float4 cfa[8];
    #pragma unroll
    for (int e = 0; e < 4; ++e) {
        cfa[2 * e]     = *(const float4*)(cp + e * 8);
        cfa[2 * e + 1] = *(const float4*)(cp + e * 8 + 4);
    }
    float4 g4 = *(const float4*)&gamma[c0];
    float4 b4 = *(const float4*)&beta[c0];

    float sm[KD_ROWS], sq[KD_ROWS];
    #pragma unroll
    for (int r = 0; r < KD_ROWS; ++r) {
        float c1 = __shfl(myc, r), s1 = __shfl(mys, r);
        float c2 = c1 * c1 - s1 * s1, s2 = 2.f * s1 * c1;
        float c3 = c2 * c1 - s2 * s1, s3 = s2 * c1 + c2 * s1;
        float ye[4];
        #pragma unroll
        for (int e = 0; e < 4; ++e) {
            float xe = (e == 0) ? yv[r].x : (e == 1) ? yv[r].y
                     : (e == 2) ? yv[r].z : yv[r].w;
            float4 A = cfa[2 * e], Bv = cfa[2 * e + 1];
            ye[e] = xe + A.x + A.y * c1 + A.z * s1 + A.w * c2
                       + Bv.x * s2 + Bv.y * c3 + Bv.z * s3;
        }
        yv[r] = make_float4(ye[0], ye[1], ye[2], ye[3]);
        sm[r] = ye[0] + ye[1] + ye[2] + ye[3];
        sq[r] = ye[0]*ye[0] + ye[1]*ye[1] + ye[2]*ye[2] + ye[3]*ye[3];
    }
    #pragma unroll
    for (int off = 1; off < 64; off <<= 1) {
        #pragma unroll
        for (int r = 0; r < KD_ROWS; ++r) {
            sm[r] += __shfl_xor(sm[r], off);
            sq[r] += __shfl_xor(sq[r], off);
        }
    }
    if (lane == 0) {
        #pragma unroll
        for (int r = 0; r < KD_ROWS; ++r) {
            red[w][r][0] = sm[r];
            red[w][r][1] = sq[r];
        }
    }
    __syncthreads();
    #pragma unroll
    for (int r = 0; r < KD_ROWS; ++r) {
        int s = s0 + r;
        float tot  = red[0][r][0] + red[1][r][0] + red[2][r][0] + red[3][r][0];
        float totq = red[0][r][1] + red[1][r][1] + red[2][r][1] + red[3][r][1];
        float mean = tot * (1.0f / (float)HH);
        float var  = totq * (1.0f / (float)HH) - mean * mean;
        float rs = rsqrtf(var + 1e-5f);
        float4 o4;
        o4.x = (yv[r].x - mean) * rs * g4.x + b4.x;
        o4.y = (yv[r].y - mean) * rs * g4.y + b4.y;
        o4.z = (yv[r].z - mean) * rs * g4.z + b4.z;
        o4.w = (yv[r].w - mean) * rs * g4.w + b4.w;
        *(float4*)&out[((size_t)(b * SS + s)) * HH + c0] = o4;
    }
}

extern "C" void kernel_launch(void* const* d_in, const int* in_sizes, int n_in,
                              void* d_out, int out_size, void* d_ws, size_t ws_size,
                              hipStream_t stream) {
    const float* x     = (const float*)d_in[0];
    const float* Wq    = (const float*)d_in[1];
    const float* bq    = (const float*)d_in[2];
    const float* wr    = (const float*)d_in[3];
    const float* wi    = (const float*)d_in[4];
    const float* gamma = (const float*)d_in[5];
    const float* beta  = (const float*)d_in[6];
    const int*   index = (const int*)d_in[7];
    float* out = (float*)d_out;
    float* ws  = (float*)d_ws;

    const size_t nP     = PPLANE * 8;          // 4M floats (16 MB)
    const size_t nSmall = (size_t)BB * HH * 8; // 32,768 floats (128 KB)

    float *P, *G, *XM, *CF;
    if (ws_size >= (nP + 3 * nSmall) * sizeof(float)) {
        P  = ws;
        G  = P + nP;
        XM = G + nSmall;
        CF = XM + nSmall;
    } else {
        // fallback: P lives in d_out (consumed by kA2 before kD writes out)
        P  = out;
        G  = ws;
        XM = G + nSmall;
        CF = XM + nSmall;
    }

    hipLaunchKernelGGL(kA_dft,     dim3(BB * NSB), dim3(256), 0, stream, x, index, P);
    hipLaunchKernelGGL(kA2_reduce, dim3(BB * HH * 8 * 4 / 256), dim3(256), 0, stream, P, G);
    hipLaunchKernelGGL(kB_proj,    dim3(BB * 256), dim3(256), 0, stream, Wq, bq, index, G, XM);
    hipLaunchKernelGGL(kC_modes,   dim3(BB * NH), dim3(512), 0, stream, wr, wi, XM, CF);
    hipLaunchKernelGGL(kD_out,     dim3(BB * (SS / KD_ROWS)), dim3(256), 0, stream, x, CF, gamma, beta, out);
}